// Round 6
// baseline (189.540 us; speedup 1.0000x reference)
//
#include <hip/hip_runtime.h>
#include <hip/hip_bf16.h>
#include <stdint.h>

#define M_TIME 64
#define N_DICT 20000
#define B_VOX  8192

#define NTILES 313    // ceil(20000/64); last tile padded with zeros

typedef _Float16 v8h __attribute__((ext_vector_type(8)));   // 8 f16 (4 VGPRs)
typedef float    v4f __attribute__((ext_vector_type(4)));
typedef float    v2f __attribute__((ext_vector_type(2)));

__device__ __forceinline__ unsigned long long u64max(unsigned long long a, unsigned long long b) { return a > b ? a : b; }
__device__ __forceinline__ unsigned umin32(unsigned a, unsigned b) { return a < b ? a : b; }
__device__ __forceinline__ unsigned umax32(unsigned a, unsigned b) { return a > b ? a : b; }
// median of 3 == second-largest of 3: one VOP3 op (pure reg computation).
__device__ __forceinline__ unsigned umed3(unsigned a, unsigned b, unsigned c) {
    unsigned d;
    asm("v_med3_u32 %0, %1, %2, %3" : "=v"(d) : "v"(a), "v"(b), "v"(c));
    return d;
}

// ---------------------------------------------------------------------------
// Prepass: convert y to f16 ONCE, packed in A-fragment order.
// Tile T = 16 fragment-rows fr = (arr*2 + h)*4 + quad; row = 64 n x 8 f16
// (k = h*32 + quad*8 + j). 16 KB/tile.
// ---------------------------------------------------------------------------
__global__ __launch_bounds__(256) void split_y(
    const float* __restrict__ yr, const float* __restrict__ yi,
    v8h* __restrict__ yp)
{
    const int u = blockIdx.x * 256 + threadIdx.x;   // [arr][T][j(8)][n_l(64)]
    const int n_l = u & 63;
    const int j   = (u >> 6) & 7;       // fragment sub-row: k = j*8 .. j*8+7
    const int T   = (u >> 9) % NTILES;
    const int arr = u / (NTILES * 512);
    if (arr > 1) return;
    const float* P = arr ? yi : yr;
    const int n_g = T * 64 + n_l;
    v8h V;
#pragma unroll
    for (int c = 0; c < 8; ++c) {
        float v = 0.f;
        if (n_g < N_DICT) v = P[(j * 8 + c) * N_DICT + n_g];
        V[c] = (_Float16)v;
    }
    const int fr = (arr * 2 + (j >> 2)) * 4 + (j & 3);   // h = j>>2, quad = j&3
    yp[((size_t)T * 16 + fr) * 64 + n_l] = V;
}

// ---------------------------------------------------------------------------
// Phase A: f16 1-term MFMA GEMM + per-chunk top-2 (u32 packed comparator).
// R17: packed-f32 sim + v_med3_u32 second-best (~4.5 VALU/elem).
// R21: LDS staging deleted (yp is L2-hot); fragments load global->VGPR,
// no barrier in the main loop. Measured: MfmaUtil 42.9 + VALUBusy 49.1
// = 92% -> pipes almost perfectly SERIALIZED per wave ([32 MFMA][88 VALU]
// program order, ~331 cyc/tile; 155/331=47%, 176/331=53% match counters).
// R22: group-pipelined emission. Tile split into 4 groups g=(nt,bt) of
// 8 MFMAs + ~20-VALU epilogue; order M0 M1 E0 M2 E1 M3 [loads] E2 E3 so
// each epilogue's VALU issues while the next group's MFMAs occupy the
// matrix pipe (true deps 1 group apart). sched_group_barrier pins the
// interleave (safe: pure reg MFMA/VALU region, no waitcnt hazards).
// Ideal issue/tile = max(155,176) vs 331 serial. Success signature:
// MfmaUtil + VALUBusy > 120%.
// History: R18 vmcnt-ring REVERTED (occupancy); R19 512-thr REVERTED
// (reg-budget spill, 727us); R20 xm-alias neutral (not LDS-bound).
// ---------------------------------------------------------------------------
__global__ __launch_bounds__(256, 2) void gemm_pre(
    const float* __restrict__ ir, const float* __restrict__ ii,
    const v8h* __restrict__ yp,
    unsigned* __restrict__ cand, int tpc, int slots)
{
    __shared__ unsigned xm[2][2][16][2];    // [wb][bt][col][a1,a2]  (512 B)

    const int tid  = threadIdx.x;
    const int wave = tid >> 6, lane = tid & 63;
    const int quad = lane >> 4, col = lane & 15;
    const int wb   = wave >> 1, wn = wave & 1;
    const int vox_w = blockIdx.x * 64 + wb * 32;
    const int chunk = blockIdx.y;
    const int T0 = chunk * tpc;
    const int T1 = (T0 + tpc < NTILES) ? T0 + tpc : NTILES;

    // ---- persistent input B-frags: [arr][bt][h] single f16 (RNE) ----
    v8h fh[2][2][2];
#pragma unroll
    for (int arr = 0; arr < 2; ++arr) {
        const float* P = arr ? ii : ir;
#pragma unroll
        for (int bt = 0; bt < 2; ++bt) {
            const int b = vox_w + bt * 16 + col;
#pragma unroll
            for (int h = 0; h < 2; ++h) {
                v8h H;
#pragma unroll
                for (int j = 0; j < 8; ++j) {
                    const int k = h * 32 + quad * 8 + j;
                    H[j] = (_Float16)P[k * B_VOX + b];
                }
                fh[arr][bt][h] = H;
            }
        }
    }

    // ---- y A-frags for the current tile, in registers ----
    v8h yfr[2][2], yfi[2][2];               // [h][nt]
    auto loadf = [&](int T) {
        const v8h* yv = (const v8h*)((const char*)yp + (size_t)T * 16384);
#pragma unroll
        for (int h = 0; h < 2; ++h)
#pragma unroll
            for (int nt = 0; nt < 2; ++nt) {
                const int nrow = (wn * 2 + nt) * 16 + col;
                yfr[h][nt] = yv[((0 * 2 + h) * 4 + quad) * 64 + nrow];
                yfi[h][nt] = yv[((1 * 2 + h) * 4 + quad) * 64 + nrow];
            }
    };

    const v4f zc = {0.f, 0.f, 0.f, 0.f};
    unsigned t2a[2] = {0u, 0u}, t2b[2] = {0u, 0u};

    loadf(T0);
    for (int T = T0; T < T1; ++T) {
        const int tl = T - T0;
        v4f a00[4], a01[4], a10[4], a11[4];   // [rr,ri,s1,s2] per group

#define MF(A, B, C) __builtin_amdgcn_mfma_f32_16x16x32_f16(A, B, C, 0, 0, 0)
        // 8 MFMAs of group (nt,bt): 4 chains of depth 2 (h=0 init, h=1 acc)
        auto mg = [&](int nt, int bt, v4f* a) {
            a[0] = MF(yfr[0][nt], fh[0][bt][0], zc);
            a[1] = MF(yfi[0][nt], fh[0][bt][0], zc);
            a[2] = MF(yfr[0][nt], fh[1][bt][0], zc);
            a[3] = MF(yfi[0][nt], fh[1][bt][0], zc);
            a[0] = MF(yfr[1][nt], fh[0][bt][1], a[0]);
            a[1] = MF(yfi[1][nt], fh[0][bt][1], a[1]);
            a[2] = MF(yfr[1][nt], fh[1][bt][1], a[2]);
            a[3] = MF(yfi[1][nt], fh[1][bt][1], a[3]);
        };
#undef MF
        // ~20-VALU epilogue of group (nt,bt): packed sim + med3 top-2
        auto eg = [&](int nt, int bt, const v4f* a) {
            const unsigned base = 0x1FFFu
                - (unsigned)(tl * 64 + (wn * 2 + nt) * 16 + quad * 4);
            v2f s01, s23;
            {
                const v2f p0 = __builtin_shufflevector(a[0], a[0], 0, 1);
                const v2f p1 = __builtin_shufflevector(a[1], a[1], 0, 1);
                const v2f p2 = __builtin_shufflevector(a[2], a[2], 0, 1);
                const v2f p3 = __builtin_shufflevector(a[3], a[3], 0, 1);
                v2f s = p0 * p0;
                s = __builtin_elementwise_fma(p1, p1, s);
                s = __builtin_elementwise_fma(p2, p2, s);
                s = __builtin_elementwise_fma(p3, p3, s);
                s01 = s;
            }
            {
                const v2f p0 = __builtin_shufflevector(a[0], a[0], 2, 3);
                const v2f p1 = __builtin_shufflevector(a[1], a[1], 2, 3);
                const v2f p2 = __builtin_shufflevector(a[2], a[2], 2, 3);
                const v2f p3 = __builtin_shufflevector(a[3], a[3], 2, 3);
                v2f s = p0 * p0;
                s = __builtin_elementwise_fma(p1, p1, s);
                s = __builtin_elementwise_fma(p2, p2, s);
                s = __builtin_elementwise_fma(p3, p3, s);
                s23 = s;
            }
#pragma unroll
            for (int r = 0; r < 4; ++r) {
                const float s = (r < 2) ? s01[r] : s23[r - 2];
                const unsigned pb = (__float_as_uint(s) & 0xFFFFE000u)
                                  | (base - (unsigned)r);
                const unsigned nb = umed3(pb, t2a[bt], t2b[bt]);  // 2nd-best
                t2a[bt] = umax32(pb, t2a[bt]);
                t2b[bt] = nb;
            }
        };

        // ---- pipelined emission: E(g) under M(g+1)'s pipe time ----
        mg(0, 0, a00);
        mg(0, 1, a01);
        eg(0, 0, a00);
        mg(1, 0, a10);
        eg(0, 1, a01);
        mg(1, 1, a11);
        if (T + 1 < T1) loadf(T + 1);       // frags(T) dead; issue T+1 loads
        eg(1, 0, a10);
        eg(1, 1, a11);

        // pin the interleave: MFMA=0x8, VALU=0x2, VMEM_READ=0x20
        __builtin_amdgcn_sched_group_barrier(0x008, 8, 0);   // M(g00)
        __builtin_amdgcn_sched_group_barrier(0x008, 8, 0);   // M(g01)
        __builtin_amdgcn_sched_group_barrier(0x002, 24, 0);  // E(g00)
        __builtin_amdgcn_sched_group_barrier(0x008, 8, 0);   // M(g10)
        __builtin_amdgcn_sched_group_barrier(0x002, 20, 0);  // E(g01)
        __builtin_amdgcn_sched_group_barrier(0x008, 8, 0);   // M(g11)
        __builtin_amdgcn_sched_group_barrier(0x020, 8, 0);   // loads T+1
        __builtin_amdgcn_sched_group_barrier(0x002, 44, 0);  // E(g10)+E(g11)
    }

    // ---- cross-lane top-2 merge over quads (lanes c, c+16, c+32, c+48) ----
    unsigned fa1[2], fa2[2];
#pragma unroll
    for (int bt = 0; bt < 2; ++bt) {
        unsigned a1 = t2a[bt], a2 = t2b[bt];
#pragma unroll
        for (int d = 16; d <= 32; d <<= 1) {
            unsigned b1 = (unsigned)__shfl_xor((int)a1, d, 64);
            unsigned b2 = (unsigned)__shfl_xor((int)a2, d, 64);
            unsigned mn = umin32(a1, b1);
            a1 = umax32(a1, b1);
            a2 = umax32(mn, umax32(a2, b2));
        }
        fa1[bt] = a1; fa2[bt] = a2;
    }
    // ---- cross-wave (wn) merge: wn==1 publishes, wn==0 writes ----
    __syncthreads();
    if (wn == 1 && lane < 16) {
#pragma unroll
        for (int bt = 0; bt < 2; ++bt) { xm[wb][bt][lane][0] = fa1[bt]; xm[wb][bt][lane][1] = fa2[bt]; }
    }
    __syncthreads();
    if (wn == 0 && lane < 16) {
#pragma unroll
        for (int bt = 0; bt < 2; ++bt) {
            unsigned b1 = xm[wb][bt][lane][0];
            unsigned b2 = xm[wb][bt][lane][1];
            unsigned m1 = umax32(fa1[bt], b1);
            unsigned m2 = umax32(umin32(fa1[bt], b1), umax32(fa2[bt], b2));
            const size_t vox = vox_w + bt * 16 + lane;
            cand[vox * slots + chunk * 2 + 0] = m1;
            cand[vox * slots + chunk * 2 + 1] = m2;
        }
    }
}

// ---------------------------------------------------------------------------
// Phase B (fused): exact fp32 rescore of candidates within 3% of approx max,
// winner lane computes scales and writes the 4 output rows directly.
// One wave per voxel.
// ---------------------------------------------------------------------------
__global__ __launch_bounds__(256) void rescore_finish(
    const float* __restrict__ ir, const float* __restrict__ ii,
    const float* __restrict__ yr, const float* __restrict__ yi,
    const float* __restrict__ inv, const float* __restrict__ x1,
    const float* __restrict__ x2,
    const unsigned* __restrict__ cand, int slots, int tpc,
    float* __restrict__ out)
{
    const int tid  = threadIdx.x;
    const int vox  = blockIdx.x * 4 + (tid >> 6);
    const int slot = tid & 63;

    unsigned p = (slot < slots) ? cand[(size_t)vox * slots + slot] : 0u;
    float sa = __uint_as_float(p & 0xFFFFE000u);
    const int chunkc = slot >> 1;
    const int nn = chunkc * tpc * 64 + (0x1FFF - (int)(p & 0x1FFFu));

    float amax = sa;
#pragma unroll
    for (int d = 1; d <= 32; d <<= 1) amax = fmaxf(amax, __shfl_xor(amax, d, 64));

    unsigned long long q = 0ull;
    float rr = 0.f, ri = 0.f, s1 = 0.f, s2 = 0.f;
    const bool active = (slot < slots) && (nn >= 0) && (nn < N_DICT)
                     && (sa >= 0.97f * amax);    // margin covers 1-term f16 error
    if (active) {
        for (int m = 0; m < M_TIME; ++m) {
            float a  = yr[(size_t)m * N_DICT + nn];
            float c  = yi[(size_t)m * N_DICT + nn];
            float vr = ir[m * B_VOX + vox];
            float vi = ii[m * B_VOX + vox];
            rr = fmaf(vr, a, rr); ri = fmaf(vr, c, ri);
            s1 = fmaf(vi, a, s1); s2 = fmaf(vi, c, s2);
        }
        float s = fmaf(rr, rr, fmaf(ri, ri, fmaf(s1, s1, s2 * s2)));
        q = (((unsigned long long)__float_as_uint(s)) << 32)
          | (unsigned long long)(0xFFFFFFFFu - (unsigned)nn);  // ties -> smaller n
    }
    unsigned long long qm = q;
#pragma unroll
    for (int d = 1; d <= 32; d <<= 1) qm = u64max(qm, __shfl_xor(qm, d, 64));

    if (active && q == qm && qm != 0ull) {       // exactly one lane (n in key)
        float ss = inv[nn];
        out[0 * B_VOX + vox] = (rr + s2) * ss;   // sum(yr*ir + yi*ii) * inv
        out[1 * B_VOX + vox] = (s1 - ri) * ss;   // sum(yr*ii - yi*ir) * inv
        out[2 * B_VOX + vox] = x1[nn];
        out[3 * B_VOX + vox] = x2[nn];
    }
}

// ---------------------------------------------------------------------------
// Last-resort fallbacks (tiny ws): fp32 brute-force argmax + finish.
// ---------------------------------------------------------------------------
__global__ __launch_bounds__(256, 3) void argmax_naive(
    const float* __restrict__ ir, const float* __restrict__ ii,
    const float* __restrict__ yr, const float* __restrict__ yi,
    int* __restrict__ idxout)
{
    int b = blockIdx.x * 256 + threadIdx.x;
    float bs = -1.0f; int bn = 0;
    for (int n = 0; n < N_DICT; ++n) {
        float a_rr = 0.f, a_ri = 0.f, a_s1 = 0.f, a_s2 = 0.f;
        for (int m = 0; m < M_TIME; ++m) {
            float a = yr[m * N_DICT + n], c = yi[m * N_DICT + n];
            float vr = ir[m * B_VOX + b], vi = ii[m * B_VOX + b];
            a_rr = fmaf(vr, a, a_rr); a_ri = fmaf(vr, c, a_ri);
            a_s1 = fmaf(vi, a, a_s1); a_s2 = fmaf(vi, c, a_s2);
        }
        float sim = fmaf(a_rr, a_rr, fmaf(a_ri, a_ri, fmaf(a_s1, a_s1, a_s2 * a_s2)));
        if (sim > bs) { bs = sim; bn = n; }
    }
    idxout[b] = bn;
}

__global__ void finish_k(const float* __restrict__ ir, const float* __restrict__ ii,
                         const float* __restrict__ yr, const float* __restrict__ yi,
                         const float* __restrict__ inv, const float* __restrict__ x1,
                         const float* __restrict__ x2,
                         const int* __restrict__ idxin, float* __restrict__ out)
{
    int b = blockIdx.x * blockDim.x + threadIdx.x;
    int idx = idxin[b];
    float ar = 0.f, ai = 0.f;
    for (int m = 0; m < M_TIME; ++m) {
        float a  = yr[(size_t)m * N_DICT + idx];
        float c  = yi[(size_t)m * N_DICT + idx];
        float vr = ir[m * B_VOX + b];
        float vi = ii[m * B_VOX + b];
        ar = fmaf(a, vr, ar); ar = fmaf(c, vi, ar);
        ai = fmaf(a, vi, ai); ai = fmaf(-c, vr, ai);
    }
    float s = inv[idx];
    out[0 * B_VOX + b] = ar * s;
    out[1 * B_VOX + b] = ai * s;
    out[2 * B_VOX + b] = x1[idx];
    out[3 * B_VOX + b] = x2[idx];
}

extern "C" void kernel_launch(void* const* d_in, const int* in_sizes, int n_in,
                              void* d_out, int out_size, void* d_ws, size_t ws_size,
                              hipStream_t stream) {
    const float* ir  = (const float*)d_in[0];
    const float* ii  = (const float*)d_in[1];
    const float* yr  = (const float*)d_in[2];
    const float* yi  = (const float*)d_in[3];
    const float* inv = (const float*)d_in[4];
    const float* x1  = (const float*)d_in[5];
    const float* x2  = (const float*)d_in[6];
    float* out = (float*)d_out;

    const size_t yp_bytes = (size_t)NTILES * 16384;    // 5.13 MB (f16 frag tiles)

    // pick largest chunk count whose cand buffer fits alongside yp (slots <= 64)
    int CH = 0;
    for (int c = 32; c >= 4; c >>= 1) {
        size_t cand_bytes = (size_t)B_VOX * (2 * c) * sizeof(unsigned);
        if (ws_size >= cand_bytes + yp_bytes) { CH = c; break; }
    }

    if (CH > 0) {
        const int slots = 2 * CH;
        const int tpc   = (NTILES + CH - 1) / CH;
        unsigned* cand = (unsigned*)d_ws;
        v8h* yp = (v8h*)((char*)d_ws + (size_t)B_VOX * slots * sizeof(unsigned));

        const int units = 2 * NTILES * 512;
        split_y<<<(units + 255) / 256, 256, 0, stream>>>(yr, yi, yp);
        gemm_pre<<<dim3(B_VOX / 64, CH), 256, 0, stream>>>(ir, ii, yp, cand, tpc, slots);
        rescore_finish<<<B_VOX / 4, 256, 0, stream>>>(ir, ii, yr, yi, inv, x1, x2,
                                                      cand, slots, tpc, out);
    } else {
        int* idxo = (int*)(out + 3 * B_VOX);   // alias out row 3 (read-before-write)
        argmax_naive<<<B_VOX / 256, 256, 0, stream>>>(ir, ii, yr, yi, idxo);
        finish_k<<<B_VOX / 256, 256, 0, stream>>>(ir, ii, yr, yi,
                                                  inv, x1, x2, idxo, out);
    }
}

// Round 7
// 187.013 us; speedup vs baseline: 1.0135x; 1.0135x over previous
//
#include <hip/hip_runtime.h>
#include <hip/hip_bf16.h>
#include <stdint.h>

#define M_TIME 64
#define N_DICT 20000
#define B_VOX  8192

#define NTILES 313    // ceil(20000/64); last tile padded with zeros

typedef _Float16 v8h __attribute__((ext_vector_type(8)));   // 8 f16 (4 VGPRs)
typedef float    v4f __attribute__((ext_vector_type(4)));
typedef float    v2f __attribute__((ext_vector_type(2)));

__device__ __forceinline__ unsigned long long u64max(unsigned long long a, unsigned long long b) { return a > b ? a : b; }
__device__ __forceinline__ unsigned umin32(unsigned a, unsigned b) { return a < b ? a : b; }
__device__ __forceinline__ unsigned umax32(unsigned a, unsigned b) { return a > b ? a : b; }
// median of 3 == second-largest of 3: one VOP3 op (pure reg computation).
__device__ __forceinline__ unsigned umed3(unsigned a, unsigned b, unsigned c) {
    unsigned d;
    asm("v_med3_u32 %0, %1, %2, %3" : "=v"(d) : "v"(a), "v"(b), "v"(c));
    return d;
}

// ---------------------------------------------------------------------------
// Prepass: convert y to f16 ONCE, packed in A-fragment order.
// Tile T = 16 fragment-rows fr = (arr*2 + h)*4 + quad; row = 64 n x 8 f16
// (k = h*32 + quad*8 + j). 16 KB/tile.
// ---------------------------------------------------------------------------
__global__ __launch_bounds__(256) void split_y(
    const float* __restrict__ yr, const float* __restrict__ yi,
    v8h* __restrict__ yp)
{
    const int u = blockIdx.x * 256 + threadIdx.x;   // [arr][T][j(8)][n_l(64)]
    const int n_l = u & 63;
    const int j   = (u >> 6) & 7;       // fragment sub-row: k = j*8 .. j*8+7
    const int T   = (u >> 9) % NTILES;
    const int arr = u / (NTILES * 512);
    if (arr > 1) return;
    const float* P = arr ? yi : yr;
    const int n_g = T * 64 + n_l;
    v8h V;
#pragma unroll
    for (int c = 0; c < 8; ++c) {
        float v = 0.f;
        if (n_g < N_DICT) v = P[(j * 8 + c) * N_DICT + n_g];
        V[c] = (_Float16)v;
    }
    const int fr = (arr * 2 + (j >> 2)) * 4 + (j & 3);   // h = j>>2, quad = j&3
    yp[((size_t)T * 16 + fr) * 64 + n_l] = V;
}

// ---------------------------------------------------------------------------
// Phase A: f16 1-term MFMA GEMM + per-chunk top-2 (u32 packed comparator).
// Counter model (R22 post-mortem): VALUBusy INCLUDES MFMA (v_mfma_* are
// VALU ops). Measured R22: MFMA pipe 41% (= the 40.5 us 16x16 roofline),
// true VALU ~8%, ~50% STALL. Stall = frag load latency: loads for T+1
// were issued late in tile T with only ~150 cyc of hiding window, and the
// 3 resident waves (identical code, in phase) stall together.
// R23: two frag register sets (A/B). Loads for T+2 issue into a set right
// after tile T consumed it -> in-flight window = the ENTIRE tile T+1
// (~1400 cyc) >> L2 latency. Compiler emits counted vmcnt(8) (other
// buffer outstanding), not a drain. 2x-unrolled loop = static buffer
// naming (no runtime-indexed frag arrays -> no scratch). Cost ~+32 VGPR
// -> occupancy tier ~8 waves/CU; R20-R22 proved occupancy is not binding.
// History: R18 vmcnt-ring REVERTED (LDS occupancy); R19 512-thr REVERTED
// (reg-budget spill); R21 LDS staging deleted (kept); R22 SGB pins
// REVERTED (neutral-negative).
// ---------------------------------------------------------------------------
__global__ __launch_bounds__(256, 2) void gemm_pre(
    const float* __restrict__ ir, const float* __restrict__ ii,
    const v8h* __restrict__ yp,
    unsigned* __restrict__ cand, int tpc, int slots)
{
    __shared__ unsigned xm[2][2][16][2];    // [wb][bt][col][a1,a2]  (512 B)

    const int tid  = threadIdx.x;
    const int wave = tid >> 6, lane = tid & 63;
    const int quad = lane >> 4, col = lane & 15;
    const int wb   = wave >> 1, wn = wave & 1;
    const int vox_w = blockIdx.x * 64 + wb * 32;
    const int chunk = blockIdx.y;
    const int T0 = chunk * tpc;
    const int T1 = (T0 + tpc < NTILES) ? T0 + tpc : NTILES;

    // ---- persistent input B-frags: [arr][bt][h] single f16 (RNE) ----
    v8h fh[2][2][2];
#pragma unroll
    for (int arr = 0; arr < 2; ++arr) {
        const float* P = arr ? ii : ir;
#pragma unroll
        for (int bt = 0; bt < 2; ++bt) {
            const int b = vox_w + bt * 16 + col;
#pragma unroll
            for (int h = 0; h < 2; ++h) {
                v8h H;
#pragma unroll
                for (int j = 0; j < 8; ++j) {
                    const int k = h * 32 + quad * 8 + j;
                    H[j] = (_Float16)P[k * B_VOX + b];
                }
                fh[arr][bt][h] = H;
            }
        }
    }

    // ---- y A-frag double buffer: two named sets (static indexing) ----
    v8h Ayr[2][2], Ayi[2][2];               // [h][nt]
    v8h Byr[2][2], Byi[2][2];

    auto loadf = [&](v8h (&fr)[2][2], v8h (&fi)[2][2], int T) {
        const v8h* yv = (const v8h*)((const char*)yp + (size_t)T * 16384);
#pragma unroll
        for (int h = 0; h < 2; ++h)
#pragma unroll
            for (int nt = 0; nt < 2; ++nt) {
                const int nrow = (wn * 2 + nt) * 16 + col;
                fr[h][nt] = yv[((0 * 2 + h) * 4 + quad) * 64 + nrow];
                fi[h][nt] = yv[((1 * 2 + h) * 4 + quad) * 64 + nrow];
            }
    };

    const v4f zc = {0.f, 0.f, 0.f, 0.f};
    unsigned t2a[2] = {0u, 0u}, t2b[2] = {0u, 0u};

#define MF(A, B, C) __builtin_amdgcn_mfma_f32_16x16x32_f16(A, B, C, 0, 0, 0)
    // 8 MFMAs of group (nt,bt): 4 chains of depth 2 (h=0 init, h=1 acc)
    auto mg = [&](v8h (&fr)[2][2], v8h (&fi)[2][2], int nt, int bt, v4f* a) {
        a[0] = MF(fr[0][nt], fh[0][bt][0], zc);
        a[1] = MF(fi[0][nt], fh[0][bt][0], zc);
        a[2] = MF(fr[0][nt], fh[1][bt][0], zc);
        a[3] = MF(fi[0][nt], fh[1][bt][0], zc);
        a[0] = MF(fr[1][nt], fh[0][bt][1], a[0]);
        a[1] = MF(fi[1][nt], fh[0][bt][1], a[1]);
        a[2] = MF(fr[1][nt], fh[1][bt][1], a[2]);
        a[3] = MF(fi[1][nt], fh[1][bt][1], a[3]);
    };
#undef MF
    // ~20-VALU epilogue of group (nt,bt): packed sim + med3 top-2
    auto eg = [&](int tl, int nt, int bt, const v4f* a) {
        const unsigned base = 0x1FFFu
            - (unsigned)(tl * 64 + (wn * 2 + nt) * 16 + quad * 4);
        v2f s01, s23;
        {
            const v2f p0 = __builtin_shufflevector(a[0], a[0], 0, 1);
            const v2f p1 = __builtin_shufflevector(a[1], a[1], 0, 1);
            const v2f p2 = __builtin_shufflevector(a[2], a[2], 0, 1);
            const v2f p3 = __builtin_shufflevector(a[3], a[3], 0, 1);
            v2f s = p0 * p0;
            s = __builtin_elementwise_fma(p1, p1, s);
            s = __builtin_elementwise_fma(p2, p2, s);
            s = __builtin_elementwise_fma(p3, p3, s);
            s01 = s;
        }
        {
            const v2f p0 = __builtin_shufflevector(a[0], a[0], 2, 3);
            const v2f p1 = __builtin_shufflevector(a[1], a[1], 2, 3);
            const v2f p2 = __builtin_shufflevector(a[2], a[2], 2, 3);
            const v2f p3 = __builtin_shufflevector(a[3], a[3], 2, 3);
            v2f s = p0 * p0;
            s = __builtin_elementwise_fma(p1, p1, s);
            s = __builtin_elementwise_fma(p2, p2, s);
            s = __builtin_elementwise_fma(p3, p3, s);
            s23 = s;
        }
#pragma unroll
        for (int r = 0; r < 4; ++r) {
            const float s = (r < 2) ? s01[r] : s23[r - 2];
            const unsigned pb = (__float_as_uint(s) & 0xFFFFE000u)
                              | (base - (unsigned)r);
            const unsigned nb = umed3(pb, t2a[bt], t2b[bt]);  // 2nd-best
            t2a[bt] = umax32(pb, t2a[bt]);
            t2b[bt] = nb;
        }
    };

    // process tile T from (fr,fi); if pfT >= 0, reload same buffer with
    // tile pfT right after the MFMAs killed it (window = next whole tile)
    auto proc = [&](v8h (&fr)[2][2], v8h (&fi)[2][2], int T, int pfT) {
        const int tl = T - T0;
        v4f a00[4], a01[4], a10[4], a11[4];
        mg(fr, fi, 0, 0, a00);
        mg(fr, fi, 0, 1, a01);
        eg(tl, 0, 0, a00);
        mg(fr, fi, 1, 0, a10);
        eg(tl, 0, 1, a01);
        mg(fr, fi, 1, 1, a11);
        if (pfT >= 0) loadf(fr, fi, pfT);   // frags dead; T+2 prefetch
        eg(tl, 1, 0, a10);
        eg(tl, 1, 1, a11);
    };

    // ---- prologue: fill both buffers ----
    loadf(Ayr, Ayi, T0);
    if (T0 + 1 < T1) loadf(Byr, Byi, T0 + 1);

    int T = T0;
    for (; T + 1 < T1; T += 2) {
        proc(Ayr, Ayi, T,     (T + 2 < T1) ? T + 2 : -1);
        proc(Byr, Byi, T + 1, (T + 3 < T1) ? T + 3 : -1);
    }
    if (T < T1) proc(Ayr, Ayi, T, -1);      // odd tail (tile is in A)

    // ---- cross-lane top-2 merge over quads (lanes c, c+16, c+32, c+48) ----
    unsigned fa1[2], fa2[2];
#pragma unroll
    for (int bt = 0; bt < 2; ++bt) {
        unsigned a1 = t2a[bt], a2 = t2b[bt];
#pragma unroll
        for (int d = 16; d <= 32; d <<= 1) {
            unsigned b1 = (unsigned)__shfl_xor((int)a1, d, 64);
            unsigned b2 = (unsigned)__shfl_xor((int)a2, d, 64);
            unsigned mn = umin32(a1, b1);
            a1 = umax32(a1, b1);
            a2 = umax32(mn, umax32(a2, b2));
        }
        fa1[bt] = a1; fa2[bt] = a2;
    }
    // ---- cross-wave (wn) merge: wn==1 publishes, wn==0 writes ----
    __syncthreads();
    if (wn == 1 && lane < 16) {
#pragma unroll
        for (int bt = 0; bt < 2; ++bt) { xm[wb][bt][lane][0] = fa1[bt]; xm[wb][bt][lane][1] = fa2[bt]; }
    }
    __syncthreads();
    if (wn == 0 && lane < 16) {
#pragma unroll
        for (int bt = 0; bt < 2; ++bt) {
            unsigned b1 = xm[wb][bt][lane][0];
            unsigned b2 = xm[wb][bt][lane][1];
            unsigned m1 = umax32(fa1[bt], b1);
            unsigned m2 = umax32(umin32(fa1[bt], b1), umax32(fa2[bt], b2));
            const size_t vox = vox_w + bt * 16 + lane;
            cand[vox * slots + chunk * 2 + 0] = m1;
            cand[vox * slots + chunk * 2 + 1] = m2;
        }
    }
}

// ---------------------------------------------------------------------------
// Phase B (fused): exact fp32 rescore of candidates within 3% of approx max,
// winner lane computes scales and writes the 4 output rows directly.
// One wave per voxel.
// ---------------------------------------------------------------------------
__global__ __launch_bounds__(256) void rescore_finish(
    const float* __restrict__ ir, const float* __restrict__ ii,
    const float* __restrict__ yr, const float* __restrict__ yi,
    const float* __restrict__ inv, const float* __restrict__ x1,
    const float* __restrict__ x2,
    const unsigned* __restrict__ cand, int slots, int tpc,
    float* __restrict__ out)
{
    const int tid  = threadIdx.x;
    const int vox  = blockIdx.x * 4 + (tid >> 6);
    const int slot = tid & 63;

    unsigned p = (slot < slots) ? cand[(size_t)vox * slots + slot] : 0u;
    float sa = __uint_as_float(p & 0xFFFFE000u);
    const int chunkc = slot >> 1;
    const int nn = chunkc * tpc * 64 + (0x1FFF - (int)(p & 0x1FFFu));

    float amax = sa;
#pragma unroll
    for (int d = 1; d <= 32; d <<= 1) amax = fmaxf(amax, __shfl_xor(amax, d, 64));

    unsigned long long q = 0ull;
    float rr = 0.f, ri = 0.f, s1 = 0.f, s2 = 0.f;
    const bool active = (slot < slots) && (nn >= 0) && (nn < N_DICT)
                     && (sa >= 0.97f * amax);    // margin covers 1-term f16 error
    if (active) {
        for (int m = 0; m < M_TIME; ++m) {
            float a  = yr[(size_t)m * N_DICT + nn];
            float c  = yi[(size_t)m * N_DICT + nn];
            float vr = ir[m * B_VOX + vox];
            float vi = ii[m * B_VOX + vox];
            rr = fmaf(vr, a, rr); ri = fmaf(vr, c, ri);
            s1 = fmaf(vi, a, s1); s2 = fmaf(vi, c, s2);
        }
        float s = fmaf(rr, rr, fmaf(ri, ri, fmaf(s1, s1, s2 * s2)));
        q = (((unsigned long long)__float_as_uint(s)) << 32)
          | (unsigned long long)(0xFFFFFFFFu - (unsigned)nn);  // ties -> smaller n
    }
    unsigned long long qm = q;
#pragma unroll
    for (int d = 1; d <= 32; d <<= 1) qm = u64max(qm, __shfl_xor(qm, d, 64));

    if (active && q == qm && qm != 0ull) {       // exactly one lane (n in key)
        float ss = inv[nn];
        out[0 * B_VOX + vox] = (rr + s2) * ss;   // sum(yr*ir + yi*ii) * inv
        out[1 * B_VOX + vox] = (s1 - ri) * ss;   // sum(yr*ii - yi*ir) * inv
        out[2 * B_VOX + vox] = x1[nn];
        out[3 * B_VOX + vox] = x2[nn];
    }
}

// ---------------------------------------------------------------------------
// Last-resort fallbacks (tiny ws): fp32 brute-force argmax + finish.
// ---------------------------------------------------------------------------
__global__ __launch_bounds__(256, 3) void argmax_naive(
    const float* __restrict__ ir, const float* __restrict__ ii,
    const float* __restrict__ yr, const float* __restrict__ yi,
    int* __restrict__ idxout)
{
    int b = blockIdx.x * 256 + threadIdx.x;
    float bs = -1.0f; int bn = 0;
    for (int n = 0; n < N_DICT; ++n) {
        float a_rr = 0.f, a_ri = 0.f, a_s1 = 0.f, a_s2 = 0.f;
        for (int m = 0; m < M_TIME; ++m) {
            float a = yr[m * N_DICT + n], c = yi[m * N_DICT + n];
            float vr = ir[m * B_VOX + b], vi = ii[m * B_VOX + b];
            a_rr = fmaf(vr, a, a_rr); a_ri = fmaf(vr, c, a_ri);
            a_s1 = fmaf(vi, a, a_s1); a_s2 = fmaf(vi, c, a_s2);
        }
        float sim = fmaf(a_rr, a_rr, fmaf(a_ri, a_ri, fmaf(a_s1, a_s1, a_s2 * a_s2)));
        if (sim > bs) { bs = sim; bn = n; }
    }
    idxout[b] = bn;
}

__global__ void finish_k(const float* __restrict__ ir, const float* __restrict__ ii,
                         const float* __restrict__ yr, const float* __restrict__ yi,
                         const float* __restrict__ inv, const float* __restrict__ x1,
                         const float* __restrict__ x2,
                         const int* __restrict__ idxin, float* __restrict__ out)
{
    int b = blockIdx.x * blockDim.x + threadIdx.x;
    int idx = idxin[b];
    float ar = 0.f, ai = 0.f;
    for (int m = 0; m < M_TIME; ++m) {
        float a  = yr[(size_t)m * N_DICT + idx];
        float c  = yi[(size_t)m * N_DICT + idx];
        float vr = ir[m * B_VOX + b];
        float vi = ii[m * B_VOX + b];
        ar = fmaf(a, vr, ar); ar = fmaf(c, vi, ar);
        ai = fmaf(a, vi, ai); ai = fmaf(-c, vr, ai);
    }
    float s = inv[idx];
    out[0 * B_VOX + b] = ar * s;
    out[1 * B_VOX + b] = ai * s;
    out[2 * B_VOX + b] = x1[idx];
    out[3 * B_VOX + b] = x2[idx];
}

extern "C" void kernel_launch(void* const* d_in, const int* in_sizes, int n_in,
                              void* d_out, int out_size, void* d_ws, size_t ws_size,
                              hipStream_t stream) {
    const float* ir  = (const float*)d_in[0];
    const float* ii  = (const float*)d_in[1];
    const float* yr  = (const float*)d_in[2];
    const float* yi  = (const float*)d_in[3];
    const float* inv = (const float*)d_in[4];
    const float* x1  = (const float*)d_in[5];
    const float* x2  = (const float*)d_in[6];
    float* out = (float*)d_out;

    const size_t yp_bytes = (size_t)NTILES * 16384;    // 5.13 MB (f16 frag tiles)

    // pick largest chunk count whose cand buffer fits alongside yp (slots <= 64)
    int CH = 0;
    for (int c = 32; c >= 4; c >>= 1) {
        size_t cand_bytes = (size_t)B_VOX * (2 * c) * sizeof(unsigned);
        if (ws_size >= cand_bytes + yp_bytes) { CH = c; break; }
    }

    if (CH > 0) {
        const int slots = 2 * CH;
        const int tpc   = (NTILES + CH - 1) / CH;
        unsigned* cand = (unsigned*)d_ws;
        v8h* yp = (v8h*)((char*)d_ws + (size_t)B_VOX * slots * sizeof(unsigned));

        const int units = 2 * NTILES * 512;
        split_y<<<(units + 255) / 256, 256, 0, stream>>>(yr, yi, yp);
        gemm_pre<<<dim3(B_VOX / 64, CH), 256, 0, stream>>>(ir, ii, yp, cand, tpc, slots);
        rescore_finish<<<B_VOX / 4, 256, 0, stream>>>(ir, ii, yr, yi, inv, x1, x2,
                                                      cand, slots, tpc, out);
    } else {
        int* idxo = (int*)(out + 3 * B_VOX);   // alias out row 3 (read-before-write)
        argmax_naive<<<B_VOX / 256, 256, 0, stream>>>(ir, ii, yr, yi, idxo);
        finish_k<<<B_VOX / 256, 256, 0, stream>>>(ir, ii, yr, yi,
                                                  inv, x1, x2, idxo, out);
    }
}

// Round 9
// 184.023 us; speedup vs baseline: 1.0300x; 1.0162x over previous
//
#include <hip/hip_runtime.h>
#include <hip/hip_bf16.h>
#include <stdint.h>

#define M_TIME 64
#define N_DICT 20000
#define B_VOX  8192

#define NTILES 313    // ceil(20000/64); last tile padded with zeros

typedef _Float16 v8h __attribute__((ext_vector_type(8)));   // 8 f16 (4 VGPRs)
typedef float    v4f __attribute__((ext_vector_type(4)));
typedef float    v2f __attribute__((ext_vector_type(2)));

__device__ __forceinline__ unsigned long long u64max(unsigned long long a, unsigned long long b) { return a > b ? a : b; }
__device__ __forceinline__ unsigned umin32(unsigned a, unsigned b) { return a < b ? a : b; }
__device__ __forceinline__ unsigned umax32(unsigned a, unsigned b) { return a > b ? a : b; }
// median of 3 == second-largest of 3: one VOP3 op (pure reg computation).
__device__ __forceinline__ unsigned umed3(unsigned a, unsigned b, unsigned c) {
    unsigned d;
    asm("v_med3_u32 %0, %1, %2, %3" : "=v"(d) : "v"(a), "v"(b), "v"(c));
    return d;
}

// ---------------------------------------------------------------------------
// Prepass: convert y to f16 ONCE, packed in A-fragment order.
// Tile T = 16 fragment-rows fr = (arr*2 + h)*4 + quad; row = 64 n x 8 f16
// (k = h*32 + quad*8 + j). 16 KB/tile.
// ---------------------------------------------------------------------------
__global__ __launch_bounds__(256) void split_y(
    const float* __restrict__ yr, const float* __restrict__ yi,
    v8h* __restrict__ yp)
{
    const int u = blockIdx.x * 256 + threadIdx.x;   // [arr][T][j(8)][n_l(64)]
    const int n_l = u & 63;
    const int j   = (u >> 6) & 7;       // fragment sub-row: k = j*8 .. j*8+7
    const int T   = (u >> 9) % NTILES;
    const int arr = u / (NTILES * 512);
    if (arr > 1) return;
    const float* P = arr ? yi : yr;
    const int n_g = T * 64 + n_l;
    v8h V;
#pragma unroll
    for (int c = 0; c < 8; ++c) {
        float v = 0.f;
        if (n_g < N_DICT) v = P[(j * 8 + c) * N_DICT + n_g];
        V[c] = (_Float16)v;
    }
    const int fr = (arr * 2 + (j >> 2)) * 4 + (j & 3);   // h = j>>2, quad = j&3
    yp[((size_t)T * 16 + fr) * 64 + n_l] = V;
}

// ---------------------------------------------------------------------------
// Phase A: f16 1-term MFMA GEMM + per-chunk top-2 (u32 packed comparator).
// Diagnosis trail: R21-R23 all land 90-95 us / MfmaUtil 42 across LDS /
// direct / SGB / reg-dbuf variants and occupancy 27-37% -> the invariant
// is per-wave FRAGMENT TRAFFIC: 8 KB/wave/tile with 2x wb-redundancy =
// 74 KB/CU/tile-period through L1 (~2355 cyc @64B/cyc) vs 1428 cyc MFMA
// demand -> L1-return-path bound at ~43% MfmaUtil. Latency depth (R23),
// emission order (R22), occupancy (R20/22) all null, as a throughput
// wall predicts.
// R24: wave output remapped 32n x 32vox -> 16n x 64vox (wave owns n-rows
// wave*16..+15, ALL 64 block-voxels, bt=0..3). Frag reads halve to
// 4 KB/wave/tile and the 4 waves read DISJOINT n-quarters: block reads
// exactly 16 KB/tile (zero redundancy). MFMA count/acc/epilogue per wave
// unchanged (32 / 64 f32 / 16 sims) - pure traffic cut, bit-identical
// math. New budget: 8 waves x 4 KB = 512 cyc L1 vs 1241 cyc MFMA ->
// MFMA-bound with 2.4x headroom. Cost: fh doubles to 16 v8h, VGPR
// ~180-200 (cap 256, 2 waves/SIMD - occupancy proven non-binding).
// (R8: resubmission of R24 unchanged - previous bench died to an
// infrastructure failure, kernel never measured.)
// History: R18 vmcnt-ring REVERTED; R19 512-thr spill REVERTED;
// R22 SGB REVERTED; R23 reg-dbuf REVERTED (all null or worse).
// ---------------------------------------------------------------------------
__global__ __launch_bounds__(256, 2) void gemm_pre(
    const float* __restrict__ ir, const float* __restrict__ ii,
    const v8h* __restrict__ yp,
    unsigned* __restrict__ cand, int tpc, int slots)
{
    __shared__ unsigned xm[4][4][16][2];    // [wave][bt][col][a1,a2]  2 KB

    const int tid  = threadIdx.x;
    const int wave = tid >> 6, lane = tid & 63;
    const int quad = lane >> 4, col = lane & 15;
    const int vox_w = blockIdx.x * 64;      // all 4 waves share the 64 voxels
    const int chunk = blockIdx.y;
    const int T0 = chunk * tpc;
    const int T1 = (T0 + tpc < NTILES) ? T0 + tpc : NTILES;

    // ---- persistent input B-frags: [arr][bt][h], bt = 0..3 (16 v8h) ----
    v8h fh[2][4][2];
#pragma unroll
    for (int arr = 0; arr < 2; ++arr) {
        const float* P = arr ? ii : ir;
#pragma unroll
        for (int bt = 0; bt < 4; ++bt) {
            const int b = vox_w + bt * 16 + col;
#pragma unroll
            for (int h = 0; h < 2; ++h) {
                v8h H;
#pragma unroll
                for (int j = 0; j < 8; ++j) {
                    const int k = h * 32 + quad * 8 + j;
                    H[j] = (_Float16)P[k * B_VOX + b];
                }
                fh[arr][bt][h] = H;
            }
        }
    }

    // ---- y A-frags: [ri][h], nrow = wave*16+col (4 v8h = 4 KB/tile) ----
    v8h yf[2][2];
    auto loadf = [&](int T) {
        const v8h* yv = (const v8h*)((const char*)yp + (size_t)T * 16384);
        const int nrow = wave * 16 + col;
#pragma unroll
        for (int ri = 0; ri < 2; ++ri)
#pragma unroll
            for (int h = 0; h < 2; ++h)
                yf[ri][h] = yv[((ri * 2 + h) * 4 + quad) * 64 + nrow];
    };

    const v4f zc = {0.f, 0.f, 0.f, 0.f};
    unsigned t2a[4] = {0u, 0u, 0u, 0u}, t2b[4] = {0u, 0u, 0u, 0u};

    loadf(T0);
    for (int T = T0; T < T1; ++T) {
        const int tl = T - T0;
        v4f acc[4][4];                      // [bt][rr,ri,s1,s2]
#define MF(A, B, C) __builtin_amdgcn_mfma_f32_16x16x32_f16(A, B, C, 0, 0, 0)
#pragma unroll
        for (int bt = 0; bt < 4; ++bt) {
            acc[bt][0] = MF(yf[0][0], fh[0][bt][0], zc);
            acc[bt][1] = MF(yf[1][0], fh[0][bt][0], zc);
            acc[bt][2] = MF(yf[0][0], fh[1][bt][0], zc);
            acc[bt][3] = MF(yf[1][0], fh[1][bt][0], zc);
        }
#pragma unroll
        for (int bt = 0; bt < 4; ++bt) {
            acc[bt][0] = MF(yf[0][1], fh[0][bt][1], acc[bt][0]);
            acc[bt][1] = MF(yf[1][1], fh[0][bt][1], acc[bt][1]);
            acc[bt][2] = MF(yf[0][1], fh[1][bt][1], acc[bt][2]);
            acc[bt][3] = MF(yf[1][1], fh[1][bt][1], acc[bt][3]);
        }
#undef MF
        // yf dead; issue next-tile loads so the epilogue runs under latency
        if (T + 1 < T1) loadf(T + 1);

        // ---- sim + top-2: packed-f32 sim, med3 second-best ----
        const unsigned base = 0x1FFFu
            - (unsigned)(tl * 64 + wave * 16 + quad * 4);
#pragma unroll
        for (int bt = 0; bt < 4; ++bt) {
            v2f s01, s23;
            {
                const v2f p0 = __builtin_shufflevector(acc[bt][0], acc[bt][0], 0, 1);
                const v2f p1 = __builtin_shufflevector(acc[bt][1], acc[bt][1], 0, 1);
                const v2f p2 = __builtin_shufflevector(acc[bt][2], acc[bt][2], 0, 1);
                const v2f p3 = __builtin_shufflevector(acc[bt][3], acc[bt][3], 0, 1);
                v2f s = p0 * p0;
                s = __builtin_elementwise_fma(p1, p1, s);
                s = __builtin_elementwise_fma(p2, p2, s);
                s = __builtin_elementwise_fma(p3, p3, s);
                s01 = s;
            }
            {
                const v2f p0 = __builtin_shufflevector(acc[bt][0], acc[bt][0], 2, 3);
                const v2f p1 = __builtin_shufflevector(acc[bt][1], acc[bt][1], 2, 3);
                const v2f p2 = __builtin_shufflevector(acc[bt][2], acc[bt][2], 2, 3);
                const v2f p3 = __builtin_shufflevector(acc[bt][3], acc[bt][3], 2, 3);
                v2f s = p0 * p0;
                s = __builtin_elementwise_fma(p1, p1, s);
                s = __builtin_elementwise_fma(p2, p2, s);
                s = __builtin_elementwise_fma(p3, p3, s);
                s23 = s;
            }
#pragma unroll
            for (int r = 0; r < 4; ++r) {       // 4 independent bt chains
                const float s = (r < 2) ? s01[r] : s23[r - 2];
                const unsigned pb = (__float_as_uint(s) & 0xFFFFE000u)
                                  | (base - (unsigned)r);
                const unsigned nb = umed3(pb, t2a[bt], t2b[bt]);  // 2nd-best
                t2a[bt] = umax32(pb, t2a[bt]);
                t2b[bt] = nb;
            }
        }
    }

    // ---- cross-lane top-2 merge over quads (lanes c, c+16, c+32, c+48) ----
    unsigned fa1[4], fa2[4];
#pragma unroll
    for (int bt = 0; bt < 4; ++bt) {
        unsigned a1 = t2a[bt], a2 = t2b[bt];
#pragma unroll
        for (int d = 16; d <= 32; d <<= 1) {
            unsigned b1 = (unsigned)__shfl_xor((int)a1, d, 64);
            unsigned b2 = (unsigned)__shfl_xor((int)a2, d, 64);
            unsigned mn = umin32(a1, b1);
            a1 = umax32(a1, b1);
            a2 = umax32(mn, umax32(a2, b2));
        }
        fa1[bt] = a1; fa2[bt] = a2;
    }
    // ---- cross-wave merge: all 4 waves publish, wave 0 merges 4-way ----
    if (lane < 16) {
#pragma unroll
        for (int bt = 0; bt < 4; ++bt) {
            xm[wave][bt][lane][0] = fa1[bt];
            xm[wave][bt][lane][1] = fa2[bt];
        }
    }
    __syncthreads();
    if (wave == 0 && lane < 16) {
#pragma unroll
        for (int bt = 0; bt < 4; ++bt) {
            unsigned m1 = 0u, m2 = 0u;
#pragma unroll
            for (int w = 0; w < 4; ++w) {
                const unsigned b1 = xm[w][bt][lane][0];
                const unsigned b2 = xm[w][bt][lane][1];
                m2 = umax32(m2, umax32(b2, umin32(m1, b1)));
                m1 = umax32(m1, b1);
            }
            const size_t vox = vox_w + bt * 16 + lane;
            cand[vox * slots + chunk * 2 + 0] = m1;
            cand[vox * slots + chunk * 2 + 1] = m2;
        }
    }
}

// ---------------------------------------------------------------------------
// Phase B (fused): exact fp32 rescore of candidates within 3% of approx max,
// winner lane computes scales and writes the 4 output rows directly.
// One wave per voxel.
// ---------------------------------------------------------------------------
__global__ __launch_bounds__(256) void rescore_finish(
    const float* __restrict__ ir, const float* __restrict__ ii,
    const float* __restrict__ yr, const float* __restrict__ yi,
    const float* __restrict__ inv, const float* __restrict__ x1,
    const float* __restrict__ x2,
    const unsigned* __restrict__ cand, int slots, int tpc,
    float* __restrict__ out)
{
    const int tid  = threadIdx.x;
    const int vox  = blockIdx.x * 4 + (tid >> 6);
    const int slot = tid & 63;

    unsigned p = (slot < slots) ? cand[(size_t)vox * slots + slot] : 0u;
    float sa = __uint_as_float(p & 0xFFFFE000u);
    const int chunkc = slot >> 1;
    const int nn = chunkc * tpc * 64 + (0x1FFF - (int)(p & 0x1FFFu));

    float amax = sa;
#pragma unroll
    for (int d = 1; d <= 32; d <<= 1) amax = fmaxf(amax, __shfl_xor(amax, d, 64));

    unsigned long long q = 0ull;
    float rr = 0.f, ri = 0.f, s1 = 0.f, s2 = 0.f;
    const bool active = (slot < slots) && (nn >= 0) && (nn < N_DICT)
                     && (sa >= 0.97f * amax);    // margin covers 1-term f16 error
    if (active) {
        for (int m = 0; m < M_TIME; ++m) {
            float a  = yr[(size_t)m * N_DICT + nn];
            float c  = yi[(size_t)m * N_DICT + nn];
            float vr = ir[m * B_VOX + vox];
            float vi = ii[m * B_VOX + vox];
            rr = fmaf(vr, a, rr); ri = fmaf(vr, c, ri);
            s1 = fmaf(vi, a, s1); s2 = fmaf(vi, c, s2);
        }
        float s = fmaf(rr, rr, fmaf(ri, ri, fmaf(s1, s1, s2 * s2)));
        q = (((unsigned long long)__float_as_uint(s)) << 32)
          | (unsigned long long)(0xFFFFFFFFu - (unsigned)nn);  // ties -> smaller n
    }
    unsigned long long qm = q;
#pragma unroll
    for (int d = 1; d <= 32; d <<= 1) qm = u64max(qm, __shfl_xor(qm, d, 64));

    if (active && q == qm && qm != 0ull) {       // exactly one lane (n in key)
        float ss = inv[nn];
        out[0 * B_VOX + vox] = (rr + s2) * ss;   // sum(yr*ir + yi*ii) * inv
        out[1 * B_VOX + vox] = (s1 - ri) * ss;   // sum(yr*ii - yi*ir) * inv
        out[2 * B_VOX + vox] = x1[nn];
        out[3 * B_VOX + vox] = x2[nn];
    }
}

// ---------------------------------------------------------------------------
// Last-resort fallbacks (tiny ws): fp32 brute-force argmax + finish.
// ---------------------------------------------------------------------------
__global__ __launch_bounds__(256, 3) void argmax_naive(
    const float* __restrict__ ir, const float* __restrict__ ii,
    const float* __restrict__ yr, const float* __restrict__ yi,
    int* __restrict__ idxout)
{
    int b = blockIdx.x * 256 + threadIdx.x;
    float bs = -1.0f; int bn = 0;
    for (int n = 0; n < N_DICT; ++n) {
        float a_rr = 0.f, a_ri = 0.f, a_s1 = 0.f, a_s2 = 0.f;
        for (int m = 0; m < M_TIME; ++m) {
            float a = yr[m * N_DICT + n], c = yi[m * N_DICT + n];
            float vr = ir[m * B_VOX + b], vi = ii[m * B_VOX + b];
            a_rr = fmaf(vr, a, a_rr); a_ri = fmaf(vr, c, a_ri);
            a_s1 = fmaf(vi, a, a_s1); a_s2 = fmaf(vi, c, a_s2);
        }
        float sim = fmaf(a_rr, a_rr, fmaf(a_ri, a_ri, fmaf(a_s1, a_s1, a_s2 * a_s2)));
        if (sim > bs) { bs = sim; bn = n; }
    }
    idxout[b] = bn;
}

__global__ void finish_k(const float* __restrict__ ir, const float* __restrict__ ii,
                         const float* __restrict__ yr, const float* __restrict__ yi,
                         const float* __restrict__ inv, const float* __restrict__ x1,
                         const float* __restrict__ x2,
                         const int* __restrict__ idxin, float* __restrict__ out)
{
    int b = blockIdx.x * blockDim.x + threadIdx.x;
    int idx = idxin[b];
    float ar = 0.f, ai = 0.f;
    for (int m = 0; m < M_TIME; ++m) {
        float a  = yr[(size_t)m * N_DICT + idx];
        float c  = yi[(size_t)m * N_DICT + idx];
        float vr = ir[m * B_VOX + b];
        float vi = ii[m * B_VOX + b];
        ar = fmaf(a, vr, ar); ar = fmaf(c, vi, ar);
        ai = fmaf(a, vi, ai); ai = fmaf(-c, vr, ai);
    }
    float s = inv[idx];
    out[0 * B_VOX + b] = ar * s;
    out[1 * B_VOX + b] = ai * s;
    out[2 * B_VOX + b] = x1[idx];
    out[3 * B_VOX + b] = x2[idx];
}

extern "C" void kernel_launch(void* const* d_in, const int* in_sizes, int n_in,
                              void* d_out, int out_size, void* d_ws, size_t ws_size,
                              hipStream_t stream) {
    const float* ir  = (const float*)d_in[0];
    const float* ii  = (const float*)d_in[1];
    const float* yr  = (const float*)d_in[2];
    const float* yi  = (const float*)d_in[3];
    const float* inv = (const float*)d_in[4];
    const float* x1  = (const float*)d_in[5];
    const float* x2  = (const float*)d_in[6];
    float* out = (float*)d_out;

    const size_t yp_bytes = (size_t)NTILES * 16384;    // 5.13 MB (f16 frag tiles)

    // pick largest chunk count whose cand buffer fits alongside yp (slots <= 64)
    int CH = 0;
    for (int c = 32; c >= 4; c >>= 1) {
        size_t cand_bytes = (size_t)B_VOX * (2 * c) * sizeof(unsigned);
        if (ws_size >= cand_bytes + yp_bytes) { CH = c; break; }
    }

    if (CH > 0) {
        const int slots = 2 * CH;
        const int tpc   = (NTILES + CH - 1) / CH;
        unsigned* cand = (unsigned*)d_ws;
        v8h* yp = (v8h*)((char*)d_ws + (size_t)B_VOX * slots * sizeof(unsigned));

        const int units = 2 * NTILES * 512;
        split_y<<<(units + 255) / 256, 256, 0, stream>>>(yr, yi, yp);
        gemm_pre<<<dim3(B_VOX / 64, CH), 256, 0, stream>>>(ir, ii, yp, cand, tpc, slots);
        rescore_finish<<<B_VOX / 4, 256, 0, stream>>>(ir, ii, yr, yi, inv, x1, x2,
                                                      cand, slots, tpc, out);
    } else {
        int* idxo = (int*)(out + 3 * B_VOX);   // alias out row 3 (read-before-write)
        argmax_naive<<<B_VOX / 256, 256, 0, stream>>>(ir, ii, yr, yi, idxo);
        finish_k<<<B_VOX / 256, 256, 0, stream>>>(ir, ii, yr, yi,
                                                  inv, x1, x2, idxo, out);
    }
}